// Round 4
// baseline (484.474 us; speedup 1.0000x reference)
//
#include <hip/hip_runtime.h>
#include <hip/hip_bf16.h>

#define LSEQ 2048
#define DM   1024
#define NH   16

typedef __attribute__((ext_vector_type(8)))  short bf16x8;
typedef __attribute__((ext_vector_type(4)))  float f32x4;
typedef __attribute__((ext_vector_type(16))) float f32x16;
typedef __attribute__((ext_vector_type(4)))  unsigned int u32x4;

#define LOG2E 1.4426950408889634f
#define C1SC  0.18033688011112042f   /* 0.125 * log2(e) */

static __device__ __forceinline__ float exp2fast(float x) {
  return __builtin_amdgcn_exp2f(x);   // v_exp_f32: computes 2^x
}

static __device__ __forceinline__ unsigned short f2bf(float f) {
  unsigned int u = __float_as_uint(f);
  u += 0x7FFFu + ((u >> 16) & 1u);
  return (unsigned short)(u >> 16);
}

static __device__ __forceinline__ float bf2f(unsigned short u) {
  return __uint_as_float(((unsigned int)u) << 16);
}

static __device__ __forceinline__ unsigned pk2(float a, float b) {
  __hip_bfloat162 t = __float22bfloat162_rn(make_float2(a, b));
  return *reinterpret_cast<unsigned*>(&t);
}

// Build PV B-fragment (16 k-values x 32 q-cols) from 8 lane-local P values.
// hi=0 lane needs words [w0,w1,partnerW0,partnerW1]; hi=1 [pW2,pW3,w2,w3].
static __device__ __forceinline__ bf16x8 mkfrag(int hi, float p0, float p1,
                                                float p2, float p3, float p4,
                                                float p5, float p6, float p7) {
  unsigned w0 = pk2(p0, p1), w1 = pk2(p2, p3);
  unsigned w2 = pk2(p4, p5), w3 = pk2(p6, p7);
  unsigned s0 = hi ? w0 : w2, s1 = hi ? w1 : w3;   // what I send across
  unsigned t0 = __shfl_xor(s0, 32, 64);
  unsigned t1 = __shfl_xor(s1, 32, 64);
  u32x4 f;
  f[0] = hi ? t0 : w0;
  f[1] = hi ? t1 : w1;
  f[2] = hi ? w2 : t0;
  f[3] = hi ? w3 : t1;
  return __builtin_bit_cast(bf16x8, f);
}

static __device__ __forceinline__ void gld_lds16(const unsigned short* g, unsigned short* l) {
  __builtin_amdgcn_global_load_lds(
      (const __attribute__((address_space(1))) unsigned int*)g,
      (__attribute__((address_space(3))) unsigned int*)l, 16, 0, 0);
}

// ---------------- data fp32 -> bf16 ----------------
__global__ void k_convert_data(const float* __restrict__ src,
                               unsigned short* __restrict__ dst, int n4) {
  int i = blockIdx.x * 256 + threadIdx.x;
  if (i >= n4) return;
  float4 v = reinterpret_cast<const float4*>(src)[i];
  ushort4 o;
  o.x = f2bf(v.x); o.y = f2bf(v.y); o.z = f2bf(v.z); o.w = f2bf(v.w);
  reinterpret_cast<ushort4*>(dst)[i] = o;
}

// ---------------- W -> Wt bf16 (transpose to [n][k]) ----------------
__global__ void k_transpose_w(const float* __restrict__ Wq,
                              const float* __restrict__ Wk,
                              const float* __restrict__ Wv,
                              unsigned short* __restrict__ Wt) {
  __shared__ unsigned short tile[64][65];
  const float* W = (blockIdx.z == 0) ? Wq : (blockIdx.z == 1) ? Wk : Wv;
  int n0 = blockIdx.x * 64, k0 = blockIdx.y * 64;
  int t = threadIdx.x;
  int c = t & 63, r0 = t >> 6;
  for (int i = 0; i < 16; ++i) {
    int r = r0 + i * 4;
    tile[r][c] = f2bf(W[(size_t)(k0 + r) * DM + n0 + c]);
  }
  __syncthreads();
  size_t nbase = (size_t)blockIdx.z * DM + n0;
  for (int i = 0; i < 16; ++i) {
    int n = r0 + i * 4;
    Wt[(nbase + n) * DM + k0 + c] = tile[c][n];
  }
}

// ---------------- mask -> maskT bf16 [kv][q], pre-scaled by log2(e) ----------------
__global__ void k_maskT(const float* __restrict__ mask,
                        unsigned short* __restrict__ maskT) {
  __shared__ float tile[64][65];
  int q0 = blockIdx.x * 64, kv0 = blockIdx.y * 64;
  int t = threadIdx.x;
  int c = t & 63, r0 = t >> 6;
  for (int i = 0; i < 16; ++i) {
    int r = r0 + i * 4;
    tile[r][c] = mask[(size_t)(q0 + r) * LSEQ + kv0 + c];
  }
  __syncthreads();
  for (int i = 0; i < 16; ++i) {
    int n = r0 + i * 4;
    maskT[(size_t)(kv0 + n) * LSEQ + q0 + c] = f2bf(tile[c][n] * LOG2E);
  }
}

// ---------------- fused QKV GEMM + bias + rotary + attn-tiled layouts ----------------
// qbuf:  [bh][2048][64]
// kbuf:  [bh][kv/32][c=d/16][kv&31][d&15]          (chunk stride 2048 elem)
// vtbuf: [bh][kv/16][dhalf][d&31][kv&15]           (chunk stride 1024 elem)
__global__ __launch_bounds__(256) void k_qkv_gemm(
    const unsigned short* __restrict__ A, const unsigned short* __restrict__ Bt,
    const float* __restrict__ bq, const float* __restrict__ bk,
    const float* __restrict__ bv, const float* __restrict__ temporal,
    unsigned short* __restrict__ qbuf, unsigned short* __restrict__ kbuf,
    unsigned short* __restrict__ vtbuf) {
  __shared__ unsigned short As[128 * 32];
  __shared__ unsigned short Bs[128 * 32];
  const int tid = threadIdx.x;
  const int lane = tid & 63, wid = tid >> 6;
  const int wm = wid >> 1, wn = wid & 1;
  const int lr = lane & 15, lg = lane >> 4;
  const int m0 = blockIdx.x * 128;
  const int n0 = blockIdx.y * 128;

  f32x4 acc[4][4] = {};

  const int e0 = tid * 8;
  const int e1 = (256 + tid) * 8;
  const int ra0 = e0 >> 5, ca0 = e0 & 31;
  const int ra1 = e1 >> 5, ca1 = e1 & 31;
  unsigned short* lA0 = As + wid * 512;
  unsigned short* lA1 = As + 2048 + wid * 512;
  unsigned short* lB0 = Bs + wid * 512;
  unsigned short* lB1 = Bs + 2048 + wid * 512;

  for (int k0 = 0; k0 < DM; k0 += 32) {
    __syncthreads();
    gld_lds16(A + (size_t)(m0 + ra0) * DM + k0 + ca0, lA0);
    gld_lds16(A + (size_t)(m0 + ra1) * DM + k0 + ca1, lA1);
    gld_lds16(Bt + (size_t)(n0 + ra0) * DM + k0 + ca0, lB0);
    gld_lds16(Bt + (size_t)(n0 + ra1) * DM + k0 + ca1, lB1);
    __syncthreads();
    bf16x8 af[4], bfv[4];
    for (int mi = 0; mi < 4; ++mi)
      af[mi] = *reinterpret_cast<const bf16x8*>(As + (wm * 64 + mi * 16 + lr) * 32 + lg * 8);
    for (int ni = 0; ni < 4; ++ni)
      bfv[ni] = *reinterpret_cast<const bf16x8*>(Bs + (wn * 64 + ni * 16 + lr) * 32 + lg * 8);
    for (int mi = 0; mi < 4; ++mi)
      for (int ni = 0; ni < 4; ++ni)
        acc[mi][ni] = __builtin_amdgcn_mfma_f32_16x16x32_bf16(af[mi], bfv[ni], acc[mi][ni], 0, 0, 0);
  }

  for (int mi = 0; mi < 4; ++mi) {
    const int mrow_base = m0 + wm * 64 + mi * 16 + lg * 4;
    for (int ni = 0; ni < 4; ++ni) {
      const int ng = n0 + wn * 64 + ni * 16 + lr;
      const int mat = ng >> 10;                 // 0=q 1=k 2=v (wave-uniform)
      const int c = ng & 1023;
      const int h = c >> 6, d = c & 63;
      const float bias = (mat == 0 ? bq : mat == 1 ? bk : bv)[c];
      f32x4 v = acc[mi][ni];
      if (mat < 2) {
        const int jj = d & 15, tt = d >> 4;
        const float fr = __expf(-(float)(jj & 14) * 0.5756462732485115f);
        const float sign = (d & 1) ? 1.f : -1.f;
        for (int j = 0; j < 4; ++j) {
          const int mrow = mrow_base + j;
          const float x = v[j] + bias;
          const float part = __shfl_xor(x, 1, 64);
          const int bb = mrow >> 11, lqs = mrow & 2047;
          const float fq = temporal[((size_t)bb * LSEQ + lqs) * 4 + tt] * fr;
          float sn, cs;
          __sincosf(fq, &sn, &cs);
          const unsigned short ov = f2bf(x * cs + sign * part * sn);
          const size_t bh = (size_t)(bb * NH + h);
          if (mat == 0) {
            qbuf[(bh * LSEQ + lqs) * 64 + d] = ov;
          } else {
            kbuf[bh * 131072 + (size_t)(lqs >> 5) * 2048 + (d >> 4) * 512 +
                 (lqs & 31) * 16 + (d & 15)] = ov;
          }
        }
      } else {
        for (int j = 0; j < 4; ++j) {
          const int mrow = mrow_base + j;
          const int bb = mrow >> 11, lqs = mrow & 2047;
          const size_t bh = (size_t)(bb * NH + h);
          vtbuf[bh * 131072 + (size_t)(lqs >> 4) * 1024 + (d >> 5) * 512 +
                (d & 31) * 16 + (lqs & 15)] = f2bf(v[j] + bias);
        }
      }
    }
  }
}

// ---------------- flash attention, swapped-operand 32x32, no inline asm ----------------
// grid (16 q-blocks, 32 bh); block 256 = 4 waves x 32 q-rows
__global__ __launch_bounds__(256) void k_attn(
    const unsigned short* __restrict__ qbuf, const unsigned short* __restrict__ kbuf,
    const unsigned short* __restrict__ vtbuf, const unsigned short* __restrict__ maskT,
    float* __restrict__ out) {
  __shared__ float otile[4][64][33];
  const int tid = threadIdx.x, lane = tid & 63, wid = tid >> 6;
  const int lq = lane & 31, hi = lane >> 5;
  const int bh = blockIdx.y;
  const int q0 = blockIdx.x * 128 + wid * 32;
  const int qg = q0 + lq;
  const size_t bhL = (size_t)bh * LSEQ;
  const unsigned short* kb = kbuf + (size_t)bh * 131072;
  const unsigned short* vb = vtbuf + (size_t)bh * 131072;

  bf16x8 qf[4];
#pragma unroll
  for (int c = 0; c < 4; ++c)
    qf[c] = *reinterpret_cast<const bf16x8*>(qbuf + (bhL + qg) * 64 + c * 16 + hi * 8);

  f32x16 o0 = {}, o1 = {};
  float m2 = -1e30f, l_run = 0.f;

  for (int kv0 = 0; kv0 < LSEQ; kv0 += 64) {
    // coalesced bf16 mask loads (maskT[kv][q], pre-scaled by log2e)
    float mk0[16], mk1[16];
#pragma unroll
    for (int r = 0; r < 16; ++r) {
      const int cr = (r & 3) + 8 * (r >> 2) + 4 * hi;
      mk0[r] = bf2f(maskT[(size_t)(kv0 + cr) * LSEQ + qg]);
      mk1[r] = bf2f(maskT[(size_t)(kv0 + 32 + cr) * LSEQ + qg]);
    }

    // S^T = K . Q^T : two 32x32 tiles, contiguous-1KB K loads
    const unsigned short* kch = kb + (size_t)(kv0 >> 5) * 2048;
    f32x16 s0 = {}, s1 = {};
#pragma unroll
    for (int c = 0; c < 4; ++c) {
      bf16x8 k0 = *reinterpret_cast<const bf16x8*>(kch + c * 512 + lq * 16 + hi * 8);
      bf16x8 k1 = *reinterpret_cast<const bf16x8*>(kch + 2048 + c * 512 + lq * 16 + hi * 8);
      s0 = __builtin_amdgcn_mfma_f32_32x32x16_bf16(k0, qf[c], s0, 0, 0, 0);
      s1 = __builtin_amdgcn_mfma_f32_32x32x16_bf16(k1, qf[c], s1, 0, 0, 0);
    }

    // into log2 domain: s2 = qk * (0.125*log2e) + mask*log2e
#pragma unroll
    for (int r = 0; r < 16; ++r) {
      s0[r] = s0[r] * C1SC + mk0[r];
      s1[r] = s1[r] * C1SC + mk1[r];
    }

    // row max (lane-local 32 + one cross-half swap)
    float loc = fmaxf(s0[0], s1[0]);
#pragma unroll
    for (int r = 1; r < 16; ++r) loc = fmaxf(loc, fmaxf(s0[r], s1[r]));
    loc = fmaxf(loc, __shfl_xor(loc, 32, 64));

    // uniform-branch rescale (exact: skip only when NO lane's max grew)
    if (!__all(loc <= m2)) {
      const float mn = fmaxf(m2, loc);
      const float al = exp2fast(m2 - mn);
      l_run *= al;
#pragma unroll
      for (int r = 0; r < 16; ++r) { o0[r] *= al; o1[r] *= al; }
      m2 = mn;
    }

    // p = 2^(s2 - m2); row-sum
    float rs = 0.f;
#pragma unroll
    for (int r = 0; r < 16; ++r) {
      s0[r] = exp2fast(s0[r] - m2); rs += s0[r];
      s1[r] = exp2fast(s1[r] - m2); rs += s1[r];
    }
    rs += __shfl_xor(rs, 32, 64);
    l_run += rs;

    // P -> bf16 B-fragments (shfl_xor based, no asm)
    bf16x8 pf0 = mkfrag(hi, s0[0], s0[1], s0[2], s0[3], s0[4], s0[5], s0[6], s0[7]);
    bf16x8 pf1 = mkfrag(hi, s0[8], s0[9], s0[10], s0[11], s0[12], s0[13], s0[14], s0[15]);
    bf16x8 pf2 = mkfrag(hi, s1[0], s1[1], s1[2], s1[3], s1[4], s1[5], s1[6], s1[7]);
    bf16x8 pf3 = mkfrag(hi, s1[8], s1[9], s1[10], s1[11], s1[12], s1[13], s1[14], s1[15]);

    // O^T += V^T . P^T : contiguous-1KB V loads
    const unsigned short* vch = vb + (size_t)(kv0 >> 4) * 1024;
#pragma unroll
    for (int ks = 0; ks < 4; ++ks) {
      bf16x8 pf = (ks == 0) ? pf0 : (ks == 1) ? pf1 : (ks == 2) ? pf2 : pf3;
      bf16x8 v0 = *reinterpret_cast<const bf16x8*>(vch + ks * 1024 + lq * 16 + hi * 8);
      bf16x8 v1 = *reinterpret_cast<const bf16x8*>(vch + ks * 1024 + 512 + lq * 16 + hi * 8);
      o0 = __builtin_amdgcn_mfma_f32_32x32x16_bf16(v0, pf, o0, 0, 0, 0);
      o1 = __builtin_amdgcn_mfma_f32_32x32x16_bf16(v1, pf, o1, 0, 0, 0);
    }
  }

  // normalize + per-wave LDS transpose + coalesced float4 stores
  const float inv = 1.f / l_run;
#pragma unroll
  for (int r = 0; r < 16; ++r) {
    const int d = (r & 3) + 8 * (r >> 2) + 4 * hi;
    otile[wid][d][lq] = o0[r] * inv;
    otile[wid][32 + d][lq] = o1[r] * inv;
  }
  __syncthreads();
  const int b = bh >> 4, h = bh & 15;
#pragma unroll
  for (int i = 0; i < 8; ++i) {
    const int u = i * 64 + lane;
    const int q = u >> 4, c4 = u & 15;
    float4 w;
    w.x = otile[wid][c4 * 4 + 0][q];
    w.y = otile[wid][c4 * 4 + 1][q];
    w.z = otile[wid][c4 * 4 + 2][q];
    w.w = otile[wid][c4 * 4 + 3][q];
    *reinterpret_cast<float4*>(out + ((size_t)(b * LSEQ + q0 + q)) * DM + h * 64 + c4 * 4) = w;
  }
}

extern "C" void kernel_launch(void* const* d_in, const int* in_sizes, int n_in,
                              void* d_out, int out_size, void* d_ws, size_t ws_size,
                              hipStream_t stream) {
  const float* data     = (const float*)d_in[0];
  const float* temporal = (const float*)d_in[1];
  const float* mask     = (const float*)d_in[2];
  const float* Wq       = (const float*)d_in[3];
  const float* bq       = (const float*)d_in[4];
  const float* Wk       = (const float*)d_in[5];
  const float* bk       = (const float*)d_in[6];
  const float* Wv       = (const float*)d_in[7];
  const float* bv       = (const float*)d_in[8];
  float* out = (float*)d_out;

  char* ws = (char*)d_ws;
  unsigned short* data_bf = (unsigned short*)(ws);                        // 8 MB (reused by maskT)
  unsigned short* wt      = (unsigned short*)(ws + (size_t)8  * 1048576); // 6 MB
  unsigned short* qbuf    = (unsigned short*)(ws + (size_t)14 * 1048576); // 8 MB
  unsigned short* kbuf    = (unsigned short*)(ws + (size_t)22 * 1048576); // 8 MB
  unsigned short* vtbuf   = (unsigned short*)(ws + (size_t)30 * 1048576); // 8 MB
  unsigned short* maskT   = data_bf;  // data_bf dead after k_qkv_gemm; maskT runs after

  hipLaunchKernelGGL(k_convert_data, dim3(4096), dim3(256), 0, stream,
                     data, data_bf, (2 * LSEQ * DM) / 4);
  hipLaunchKernelGGL(k_transpose_w, dim3(16, 16, 3), dim3(256), 0, stream,
                     Wq, Wk, Wv, wt);
  hipLaunchKernelGGL(k_qkv_gemm, dim3(32, 24), dim3(256), 0, stream,
                     data_bf, wt, bq, bk, bv, temporal, qbuf, kbuf, vtbuf);
  hipLaunchKernelGGL(k_maskT, dim3(32, 32), dim3(256), 0, stream,
                     mask, maskT);
  hipLaunchKernelGGL(k_attn, dim3(16, 32), dim3(256), 0, stream,
                     qbuf, kbuf, vtbuf, maskT, out);
}

// Round 5
// 158.082 us; speedup vs baseline: 3.0647x; 3.0647x over previous
//
#include <hip/hip_runtime.h>
#include <hip/hip_bf16.h>

#define LSEQ 2048
#define DM   1024
#define NH   16

typedef __attribute__((ext_vector_type(8)))  short bf16x8;
typedef __attribute__((ext_vector_type(8)))  unsigned short u16x8;
typedef __attribute__((ext_vector_type(4)))  float f32x4;
typedef __attribute__((ext_vector_type(16))) float f32x16;
typedef __attribute__((ext_vector_type(4)))  unsigned int u32x4;

#define LOG2E 1.4426950408889634f
#define C1SC  0.18033688011112042f   /* 0.125 * log2(e) */

static __device__ __forceinline__ float exp2fast(float x) {
  return __builtin_amdgcn_exp2f(x);   // v_exp_f32: computes 2^x
}

static __device__ __forceinline__ unsigned short f2bf(float f) {
  unsigned int u = __float_as_uint(f);
  u += 0x7FFFu + ((u >> 16) & 1u);
  return (unsigned short)(u >> 16);
}

static __device__ __forceinline__ float bf2f(unsigned short u) {
  return __uint_as_float(((unsigned int)u) << 16);
}

static __device__ __forceinline__ unsigned pk2(float a, float b) {
  __hip_bfloat162 t = __float22bfloat162_rn(make_float2(a, b));
  return *reinterpret_cast<unsigned*>(&t);
}

// Build PV B-fragment (16 k-values x 32 q-cols) from 8 lane-local P values.
static __device__ __forceinline__ bf16x8 mkfrag(int hi, float p0, float p1,
                                                float p2, float p3, float p4,
                                                float p5, float p6, float p7) {
  unsigned w0 = pk2(p0, p1), w1 = pk2(p2, p3);
  unsigned w2 = pk2(p4, p5), w3 = pk2(p6, p7);
  unsigned s0 = hi ? w0 : w2, s1 = hi ? w1 : w3;
  unsigned t0 = __shfl_xor(s0, 32, 64);
  unsigned t1 = __shfl_xor(s1, 32, 64);
  u32x4 f;
  f[0] = hi ? t0 : w0;
  f[1] = hi ? t1 : w1;
  f[2] = hi ? w2 : t0;
  f[3] = hi ? w3 : t1;
  return __builtin_bit_cast(bf16x8, f);
}

static __device__ __forceinline__ void gld_lds16(const unsigned short* g, unsigned short* l) {
  __builtin_amdgcn_global_load_lds(
      (const __attribute__((address_space(1))) unsigned int*)g,
      (__attribute__((address_space(3))) unsigned int*)l, 16, 0, 0);
}

// ---------------- data fp32 -> bf16 ----------------
__global__ void k_convert_data(const float* __restrict__ src,
                               unsigned short* __restrict__ dst, int n4) {
  int i = blockIdx.x * 256 + threadIdx.x;
  if (i >= n4) return;
  float4 v = reinterpret_cast<const float4*>(src)[i];
  ushort4 o;
  o.x = f2bf(v.x); o.y = f2bf(v.y); o.z = f2bf(v.z); o.w = f2bf(v.w);
  reinterpret_cast<ushort4*>(dst)[i] = o;
}

// ---------------- W -> Wt bf16 (transpose to [n][k]) ----------------
__global__ void k_transpose_w(const float* __restrict__ Wq,
                              const float* __restrict__ Wk,
                              const float* __restrict__ Wv,
                              unsigned short* __restrict__ Wt) {
  __shared__ unsigned short tile[64][65];
  const float* W = (blockIdx.z == 0) ? Wq : (blockIdx.z == 1) ? Wk : Wv;
  int n0 = blockIdx.x * 64, k0 = blockIdx.y * 64;
  int t = threadIdx.x;
  int c = t & 63, r0 = t >> 6;
  for (int i = 0; i < 16; ++i) {
    int r = r0 + i * 4;
    tile[r][c] = f2bf(W[(size_t)(k0 + r) * DM + n0 + c]);
  }
  __syncthreads();
  size_t nbase = (size_t)blockIdx.z * DM + n0;
  for (int i = 0; i < 16; ++i) {
    int n = r0 + i * 4;
    Wt[(nbase + n) * DM + k0 + c] = tile[c][n];
  }
}

// ---------------- mask -> maskT bf16 [kv][q], pre-scaled by log2(e) ----------------
__global__ void k_maskT(const float* __restrict__ mask,
                        unsigned short* __restrict__ maskT) {
  __shared__ float tile[64][65];
  int q0 = blockIdx.x * 64, kv0 = blockIdx.y * 64;
  int t = threadIdx.x;
  int c = t & 63, r0 = t >> 6;
  for (int i = 0; i < 16; ++i) {
    int r = r0 + i * 4;
    tile[r][c] = mask[(size_t)(q0 + r) * LSEQ + kv0 + c];
  }
  __syncthreads();
  for (int i = 0; i < 16; ++i) {
    int n = r0 + i * 4;
    maskT[(size_t)(kv0 + n) * LSEQ + q0 + c] = f2bf(tile[c][n] * LOG2E);
  }
}

// ---------------- fused QKV GEMM + bias + rotary + attn-tiled layouts ----------------
// qbuf:  [bh][2048][64]
// kbuf:  [bh][kv/32][c=d/16][kv&31][d&15]          (chunk stride 2048 elem)
// vtbuf: [bh][kv/16][dhalf][d&31][kv&15]           (chunk stride 1024 elem)
// Epilogue: LDS-staged, all global stores are coalesced 16B ushort8.
__global__ __launch_bounds__(256) void k_qkv_gemm(
    const unsigned short* __restrict__ A, const unsigned short* __restrict__ Bt,
    const float* __restrict__ bq, const float* __restrict__ bk,
    const float* __restrict__ bv, const float* __restrict__ temporal,
    unsigned short* __restrict__ qbuf, unsigned short* __restrict__ kbuf,
    unsigned short* __restrict__ vtbuf) {
  __shared__ unsigned short As[128 * 32];
  __shared__ unsigned short Bs[128 * 32];
  __shared__ unsigned short otile[128 * 136];   // 16B-aligned rows (136*2=272=17*16)
  const int tid = threadIdx.x;
  const int lane = tid & 63, wid = tid >> 6;
  const int wm = wid >> 1, wn = wid & 1;
  const int lr = lane & 15, lg = lane >> 4;

  // XCD-aware swizzle: each XCD owns 4 m-panels x all 24 n-panels (A L2-resident)
  const int bid = blockIdx.x;
  const int xcd = bid & 7, rr = bid >> 3;         // rr in [0,96)
  const int mblk = xcd * 4 + (rr / 24);
  const int nblk = rr % 24;
  const int m0 = mblk * 128;
  const int n0 = nblk * 128;

  f32x4 acc[4][4] = {};

  const int e0 = tid * 8;
  const int e1 = (256 + tid) * 8;
  const int ra0 = e0 >> 5, ca0 = e0 & 31;
  const int ra1 = e1 >> 5, ca1 = e1 & 31;
  unsigned short* lA0 = As + wid * 512;
  unsigned short* lA1 = As + 2048 + wid * 512;
  unsigned short* lB0 = Bs + wid * 512;
  unsigned short* lB1 = Bs + 2048 + wid * 512;

  for (int k0 = 0; k0 < DM; k0 += 32) {
    __syncthreads();
    gld_lds16(A + (size_t)(m0 + ra0) * DM + k0 + ca0, lA0);
    gld_lds16(A + (size_t)(m0 + ra1) * DM + k0 + ca1, lA1);
    gld_lds16(Bt + (size_t)(n0 + ra0) * DM + k0 + ca0, lB0);
    gld_lds16(Bt + (size_t)(n0 + ra1) * DM + k0 + ca1, lB1);
    __syncthreads();
    bf16x8 af[4], bfv[4];
    for (int mi = 0; mi < 4; ++mi)
      af[mi] = *reinterpret_cast<const bf16x8*>(As + (wm * 64 + mi * 16 + lr) * 32 + lg * 8);
    for (int ni = 0; ni < 4; ++ni)
      bfv[ni] = *reinterpret_cast<const bf16x8*>(Bs + (wn * 64 + ni * 16 + lr) * 32 + lg * 8);
    for (int mi = 0; mi < 4; ++mi)
      for (int ni = 0; ni < 4; ++ni)
        acc[mi][ni] = __builtin_amdgcn_mfma_f32_16x16x32_bf16(af[mi], bfv[ni], acc[mi][ni], 0, 0, 0);
  }

  // ---- phase 1: compute bias/rotary, stage into LDS tile ----
  const int mat = n0 >> 10;          // block-uniform: 0=q 1=k 2=v
  const int c0 = n0 & 1023;
  const int bb = m0 >> 11;           // block-uniform batch
  const int mloc = m0 & 2047;

  for (int mi = 0; mi < 4; ++mi) {
    const int rrel_base = wm * 64 + mi * 16 + lg * 4;
    for (int ni = 0; ni < 4; ++ni) {
      const int crel = wn * 64 + ni * 16 + lr;     // 0..127 within tile
      const int c = (c0 + crel);
      const int d = c & 63;
      const float bias = (mat == 0 ? bq : mat == 1 ? bk : bv)[c];
      f32x4 v = acc[mi][ni];
      if (mat < 2) {
        const int jj = d & 15, tt = d >> 4;
        const float fr = __expf(-(float)(jj & 14) * 0.5756462732485115f);
        const float sign = (d & 1) ? 1.f : -1.f;
        for (int j = 0; j < 4; ++j) {
          const int rrel = rrel_base + j;
          const float x = v[j] + bias;
          const float part = __shfl_xor(x, 1, 64);
          const int lqs = mloc + rrel;
          const float fq = temporal[((size_t)bb * LSEQ + lqs) * 4 + tt] * fr;
          float sn, cs;
          __sincosf(fq, &sn, &cs);
          otile[rrel * 136 + crel] = f2bf(x * cs + sign * part * sn);
        }
      } else {
        for (int j = 0; j < 4; ++j) {
          const int rrel = rrel_base + j;
          otile[crel * 136 + rrel] = f2bf(v[j] + bias);   // transposed for V
        }
      }
    }
  }
  __syncthreads();

  // ---- phase 2: coalesced 16B stores; per head, dst region is 8192 contiguous elems ----
  for (int i = 0; i < 2; ++i) {
    const int h = (c0 >> 6) + i;
    const size_t bh = (size_t)(bb * NH + h);
    if (mat == 0) {
      const size_t base = (bh * LSEQ + mloc) * 64;
#pragma unroll
      for (int kk2 = 0; kk2 < 4; ++kk2) {
        const int e = kk2 * 2048 + tid * 8;
        const int r = e >> 6, d = e & 63;
        *reinterpret_cast<u16x8*>(qbuf + base + e) =
            *reinterpret_cast<const u16x8*>(otile + r * 136 + i * 64 + d);
      }
    } else if (mat == 1) {
      const size_t base = bh * 131072 + (size_t)(mloc >> 5) * 2048;
#pragma unroll
      for (int kk2 = 0; kk2 < 4; ++kk2) {
        const int e = kk2 * 2048 + tid * 8;
        const int r = kk2 * 32 + ((tid >> 1) & 31);
        const int d = ((tid >> 6) & 3) * 16 + (tid & 1) * 8;
        *reinterpret_cast<u16x8*>(kbuf + base + e) =
            *reinterpret_cast<const u16x8*>(otile + r * 136 + i * 64 + d);
      }
    } else {
      const size_t base = bh * 131072 + (size_t)(mloc >> 4) * 1024;
#pragma unroll
      for (int kk2 = 0; kk2 < 4; ++kk2) {
        const int e = kk2 * 2048 + tid * 8;
        const int d = ((tid >> 6) & 1) * 32 + ((tid >> 1) & 31);
        const int r = (kk2 * 2 + (tid >> 7)) * 16 + (tid & 1) * 8;
        *reinterpret_cast<u16x8*>(vtbuf + base + e) =
            *reinterpret_cast<const u16x8*>(otile + (i * 64 + d) * 136 + r);
      }
    }
  }
}

// ---------------- flash attention, swapped-operand 32x32 ----------------
// grid (16 q-blocks, 32 bh); block 256 = 4 waves x 32 q-rows
__global__ __launch_bounds__(256) void k_attn(
    const unsigned short* __restrict__ qbuf, const unsigned short* __restrict__ kbuf,
    const unsigned short* __restrict__ vtbuf, const unsigned short* __restrict__ maskT,
    float* __restrict__ out) {
  __shared__ float otile[4][64][33];
  const int tid = threadIdx.x, lane = tid & 63, wid = tid >> 6;
  const int lq = lane & 31, hi = lane >> 5;
  const int bh = blockIdx.y;
  const int q0 = blockIdx.x * 128 + wid * 32;
  const int qg = q0 + lq;
  const size_t bhL = (size_t)bh * LSEQ;
  const unsigned short* kb = kbuf + (size_t)bh * 131072;
  const unsigned short* vb = vtbuf + (size_t)bh * 131072;

  bf16x8 qf[4];
#pragma unroll
  for (int c = 0; c < 4; ++c)
    qf[c] = *reinterpret_cast<const bf16x8*>(qbuf + (bhL + qg) * 64 + c * 16 + hi * 8);

  f32x16 o0 = {}, o1 = {};
  float m2 = -1e30f, l_run = 0.f;

  for (int kv0 = 0; kv0 < LSEQ; kv0 += 64) {
    float mk0[16], mk1[16];
#pragma unroll
    for (int r = 0; r < 16; ++r) {
      const int cr = (r & 3) + 8 * (r >> 2) + 4 * hi;
      mk0[r] = bf2f(maskT[(size_t)(kv0 + cr) * LSEQ + qg]);
      mk1[r] = bf2f(maskT[(size_t)(kv0 + 32 + cr) * LSEQ + qg]);
    }

    const unsigned short* kch = kb + (size_t)(kv0 >> 5) * 2048;
    f32x16 s0 = {}, s1 = {};
#pragma unroll
    for (int c = 0; c < 4; ++c) {
      bf16x8 k0 = *reinterpret_cast<const bf16x8*>(kch + c * 512 + lq * 16 + hi * 8);
      bf16x8 k1 = *reinterpret_cast<const bf16x8*>(kch + 2048 + c * 512 + lq * 16 + hi * 8);
      s0 = __builtin_amdgcn_mfma_f32_32x32x16_bf16(k0, qf[c], s0, 0, 0, 0);
      s1 = __builtin_amdgcn_mfma_f32_32x32x16_bf16(k1, qf[c], s1, 0, 0, 0);
    }

#pragma unroll
    for (int r = 0; r < 16; ++r) {
      s0[r] = s0[r] * C1SC + mk0[r];
      s1[r] = s1[r] * C1SC + mk1[r];
    }

    float loc = fmaxf(s0[0], s1[0]);
#pragma unroll
    for (int r = 1; r < 16; ++r) loc = fmaxf(loc, fmaxf(s0[r], s1[r]));
    loc = fmaxf(loc, __shfl_xor(loc, 32, 64));

    if (!__all(loc <= m2)) {
      const float mn = fmaxf(m2, loc);
      const float al = exp2fast(m2 - mn);
      l_run *= al;
#pragma unroll
      for (int r = 0; r < 16; ++r) { o0[r] *= al; o1[r] *= al; }
      m2 = mn;
    }

    float rs = 0.f;
#pragma unroll
    for (int r = 0; r < 16; ++r) {
      s0[r] = exp2fast(s0[r] - m2); rs += s0[r];
      s1[r] = exp2fast(s1[r] - m2); rs += s1[r];
    }
    rs += __shfl_xor(rs, 32, 64);
    l_run += rs;

    bf16x8 pf0 = mkfrag(hi, s0[0], s0[1], s0[2], s0[3], s0[4], s0[5], s0[6], s0[7]);
    bf16x8 pf1 = mkfrag(hi, s0[8], s0[9], s0[10], s0[11], s0[12], s0[13], s0[14], s0[15]);
    bf16x8 pf2 = mkfrag(hi, s1[0], s1[1], s1[2], s1[3], s1[4], s1[5], s1[6], s1[7]);
    bf16x8 pf3 = mkfrag(hi, s1[8], s1[9], s1[10], s1[11], s1[12], s1[13], s1[14], s1[15]);

    const unsigned short* vch = vb + (size_t)(kv0 >> 4) * 1024;
#pragma unroll
    for (int ks = 0; ks < 4; ++ks) {
      bf16x8 pf = (ks == 0) ? pf0 : (ks == 1) ? pf1 : (ks == 2) ? pf2 : pf3;
      bf16x8 v0 = *reinterpret_cast<const bf16x8*>(vch + ks * 1024 + lq * 16 + hi * 8);
      bf16x8 v1 = *reinterpret_cast<const bf16x8*>(vch + ks * 1024 + 512 + lq * 16 + hi * 8);
      o0 = __builtin_amdgcn_mfma_f32_32x32x16_bf16(v0, pf, o0, 0, 0, 0);
      o1 = __builtin_amdgcn_mfma_f32_32x32x16_bf16(v1, pf, o1, 0, 0, 0);
    }
  }

  const float inv = 1.f / l_run;
#pragma unroll
  for (int r = 0; r < 16; ++r) {
    const int d = (r & 3) + 8 * (r >> 2) + 4 * hi;
    otile[wid][d][lq] = o0[r] * inv;
    otile[wid][32 + d][lq] = o1[r] * inv;
  }
  __syncthreads();
  const int b = bh >> 4, h = bh & 15;
#pragma unroll
  for (int i = 0; i < 8; ++i) {
    const int u = i * 64 + lane;
    const int q = u >> 4, c4 = u & 15;
    float4 w;
    w.x = otile[wid][c4 * 4 + 0][q];
    w.y = otile[wid][c4 * 4 + 1][q];
    w.z = otile[wid][c4 * 4 + 2][q];
    w.w = otile[wid][c4 * 4 + 3][q];
    *reinterpret_cast<float4*>(out + ((size_t)(b * LSEQ + q0 + q)) * DM + h * 64 + c4 * 4) = w;
  }
}

extern "C" void kernel_launch(void* const* d_in, const int* in_sizes, int n_in,
                              void* d_out, int out_size, void* d_ws, size_t ws_size,
                              hipStream_t stream) {
  const float* data     = (const float*)d_in[0];
  const float* temporal = (const float*)d_in[1];
  const float* mask     = (const float*)d_in[2];
  const float* Wq       = (const float*)d_in[3];
  const float* bq       = (const float*)d_in[4];
  const float* Wk       = (const float*)d_in[5];
  const float* bk       = (const float*)d_in[6];
  const float* Wv       = (const float*)d_in[7];
  const float* bv       = (const float*)d_in[8];
  float* out = (float*)d_out;

  char* ws = (char*)d_ws;
  unsigned short* data_bf = (unsigned short*)(ws);                        // 8 MB (reused by maskT)
  unsigned short* wt      = (unsigned short*)(ws + (size_t)8  * 1048576); // 6 MB
  unsigned short* qbuf    = (unsigned short*)(ws + (size_t)14 * 1048576); // 8 MB
  unsigned short* kbuf    = (unsigned short*)(ws + (size_t)22 * 1048576); // 8 MB
  unsigned short* vtbuf   = (unsigned short*)(ws + (size_t)30 * 1048576); // 8 MB
  unsigned short* maskT   = data_bf;  // data_bf dead after k_qkv_gemm; maskT runs after

  hipLaunchKernelGGL(k_convert_data, dim3(4096), dim3(256), 0, stream,
                     data, data_bf, (2 * LSEQ * DM) / 4);
  hipLaunchKernelGGL(k_transpose_w, dim3(16, 16, 3), dim3(256), 0, stream,
                     Wq, Wk, Wv, wt);
  hipLaunchKernelGGL(k_qkv_gemm, dim3(768), dim3(256), 0, stream,
                     data_bf, wt, bq, bk, bv, temporal, qbuf, kbuf, vtbuf);
  hipLaunchKernelGGL(k_maskT, dim3(32, 32), dim3(256), 0, stream,
                     mask, maskT);
  hipLaunchKernelGGL(k_attn, dim3(16, 32), dim3(256), 0, stream,
                     qbuf, kbuf, vtbuf, maskT, out);
}

// Round 6
// 138.416 us; speedup vs baseline: 3.5001x; 1.1421x over previous
//
#include <hip/hip_runtime.h>
#include <hip/hip_bf16.h>

#define LSEQ 2048
#define DM   1024
#define NH   16

typedef __attribute__((ext_vector_type(8)))  short bf16x8;
typedef __attribute__((ext_vector_type(8)))  unsigned short u16x8;
typedef __attribute__((ext_vector_type(4)))  float f32x4;
typedef __attribute__((ext_vector_type(16))) float f32x16;
typedef __attribute__((ext_vector_type(4)))  unsigned int u32x4;

#define LOG2E 1.4426950408889634f
#define C1SC  0.18033688011112042f   /* 0.125 * log2(e) */
#define DEFER_THR 8.0f               /* log2-domain defer-max threshold (P <= 256) */

static __device__ __forceinline__ float exp2fast(float x) {
  return __builtin_amdgcn_exp2f(x);   // v_exp_f32: computes 2^x
}

static __device__ __forceinline__ unsigned short f2bf(float f) {
  unsigned int u = __float_as_uint(f);
  u += 0x7FFFu + ((u >> 16) & 1u);
  return (unsigned short)(u >> 16);
}

static __device__ __forceinline__ unsigned pk2(float a, float b) {
  __hip_bfloat162 t = __float22bfloat162_rn(make_float2(a, b));
  return *reinterpret_cast<unsigned*>(&t);
}

// unpack 16 packed bf16 (two 16B vectors) -> f32x16
static __device__ __forceinline__ f32x16 unpack16(u16x8 a, u16x8 b) {
  const u32x4 ua = __builtin_bit_cast(u32x4, a);
  const u32x4 ub = __builtin_bit_cast(u32x4, b);
  f32x16 r;
#pragma unroll
  for (int i = 0; i < 4; ++i) {
    r[2 * i]     = __uint_as_float(ua[i] << 16);
    r[2 * i + 1] = __uint_as_float(ua[i] & 0xFFFF0000u);
    r[8 + 2 * i]     = __uint_as_float(ub[i] << 16);
    r[8 + 2 * i + 1] = __uint_as_float(ub[i] & 0xFFFF0000u);
  }
  return r;
}

// Build PV B-fragment (16 k-values x 32 q-cols) from 8 lane-local P values.
static __device__ __forceinline__ bf16x8 mkfrag(int hi, float p0, float p1,
                                                float p2, float p3, float p4,
                                                float p5, float p6, float p7) {
  unsigned w0 = pk2(p0, p1), w1 = pk2(p2, p3);
  unsigned w2 = pk2(p4, p5), w3 = pk2(p6, p7);
  unsigned s0 = hi ? w0 : w2, s1 = hi ? w1 : w3;
  unsigned t0 = __shfl_xor(s0, 32, 64);
  unsigned t1 = __shfl_xor(s1, 32, 64);
  u32x4 f;
  f[0] = hi ? t0 : w0;
  f[1] = hi ? t1 : w1;
  f[2] = hi ? w2 : t0;
  f[3] = hi ? w3 : t1;
  return __builtin_bit_cast(bf16x8, f);
}

static __device__ __forceinline__ void gld_lds16(const unsigned short* g, unsigned short* l) {
  __builtin_amdgcn_global_load_lds(
      (const __attribute__((address_space(1))) unsigned int*)g,
      (__attribute__((address_space(3))) unsigned int*)l, 16, 0, 0);
}

// ---------------- data fp32 -> bf16 ----------------
__global__ void k_convert_data(const float* __restrict__ src,
                               unsigned short* __restrict__ dst, int n4) {
  int i = blockIdx.x * 256 + threadIdx.x;
  if (i >= n4) return;
  float4 v = reinterpret_cast<const float4*>(src)[i];
  ushort4 o;
  o.x = f2bf(v.x); o.y = f2bf(v.y); o.z = f2bf(v.z); o.w = f2bf(v.w);
  reinterpret_cast<ushort4*>(dst)[i] = o;
}

// ---------------- W -> Wt bf16 (transpose to [n][k]) ----------------
__global__ void k_transpose_w(const float* __restrict__ Wq,
                              const float* __restrict__ Wk,
                              const float* __restrict__ Wv,
                              unsigned short* __restrict__ Wt) {
  __shared__ unsigned short tile[64][65];
  const float* W = (blockIdx.z == 0) ? Wq : (blockIdx.z == 1) ? Wk : Wv;
  int n0 = blockIdx.x * 64, k0 = blockIdx.y * 64;
  int t = threadIdx.x;
  int c = t & 63, r0 = t >> 6;
  for (int i = 0; i < 16; ++i) {
    int r = r0 + i * 4;
    tile[r][c] = f2bf(W[(size_t)(k0 + r) * DM + n0 + c]);
  }
  __syncthreads();
  size_t nbase = (size_t)blockIdx.z * DM + n0;
  for (int i = 0; i < 16; ++i) {
    int n = r0 + i * 4;
    Wt[(nbase + n) * DM + k0 + c] = tile[c][n];
  }
}

// ---------------- mask -> maskCb: bf16 in MFMA C-fragment layout, *log2e ----------------
// maskCb[((kv0/64)*4 + t*2 + hi) * 2048 + q][16]: r=0..15 -> kv_local = 32t+4hi+(r&3)+8(r>>2)
__global__ void k_maskC(const float* __restrict__ mask,
                        unsigned short* __restrict__ maskCb) {
  __shared__ float tile[64][65];
  int q0 = blockIdx.x * 64, kv0 = blockIdx.y * 64;
  int t = threadIdx.x;
  int c = t & 63, r0 = t >> 6;
  for (int i = 0; i < 16; ++i) {
    int r = r0 + i * 4;
    tile[r][c] = mask[(size_t)(q0 + r) * LSEQ + kv0 + c];
  }
  __syncthreads();
  const int q = t & 63, slot = t >> 6;         // slot = tt*2 + hh
  const int tt = slot >> 1, hh = slot & 1;
  u16x8 va, vb;
#pragma unroll
  for (int r = 0; r < 8; ++r) {
    const int kvloc = 32 * tt + 4 * hh + (r & 3) + 8 * (r >> 2);
    va[r] = f2bf(tile[q][kvloc] * LOG2E);
  }
#pragma unroll
  for (int r = 8; r < 16; ++r) {
    const int kvloc = 32 * tt + 4 * hh + (r & 3) + 8 * (r >> 2);
    vb[r - 8] = f2bf(tile[q][kvloc] * LOG2E);
  }
  unsigned short* dst = maskCb + ((size_t)((kv0 >> 6) * 4 + slot) * 2048 + q0 + q) * 16;
  *reinterpret_cast<u16x8*>(dst) = va;
  *reinterpret_cast<u16x8*>(dst + 8) = vb;
}

// ---------------- fused QKV GEMM + bias + rotary (+Q pre-scale) + attn-tiled layouts ----------------
// qbuf:  [bh][2048][64]   (Q pre-scaled by 0.125*log2e)
// kbuf:  [bh][kv/32][c=d/16][kv&31][d&15]          (chunk stride 2048 elem)
// vtbuf: [bh][kv/16][dhalf][d&31][kv&15]           (chunk stride 1024 elem)
__global__ __launch_bounds__(256) void k_qkv_gemm(
    const unsigned short* __restrict__ A, const unsigned short* __restrict__ Bt,
    const float* __restrict__ bq, const float* __restrict__ bk,
    const float* __restrict__ bv, const float* __restrict__ temporal,
    unsigned short* __restrict__ qbuf, unsigned short* __restrict__ kbuf,
    unsigned short* __restrict__ vtbuf) {
  __shared__ unsigned short As[128 * 32];
  __shared__ unsigned short Bs[128 * 32];
  __shared__ unsigned short otile[128 * 136];
  const int tid = threadIdx.x;
  const int lane = tid & 63, wid = tid >> 6;
  const int wm = wid >> 1, wn = wid & 1;
  const int lr = lane & 15, lg = lane >> 4;

  const int bid = blockIdx.x;
  const int xcd = bid & 7, rr = bid >> 3;
  const int mblk = xcd * 4 + (rr / 24);
  const int nblk = rr % 24;
  const int m0 = mblk * 128;
  const int n0 = nblk * 128;

  f32x4 acc[4][4] = {};

  const int e0 = tid * 8;
  const int e1 = (256 + tid) * 8;
  const int ra0 = e0 >> 5, ca0 = e0 & 31;
  const int ra1 = e1 >> 5, ca1 = e1 & 31;
  unsigned short* lA0 = As + wid * 512;
  unsigned short* lA1 = As + 2048 + wid * 512;
  unsigned short* lB0 = Bs + wid * 512;
  unsigned short* lB1 = Bs + 2048 + wid * 512;

  for (int k0 = 0; k0 < DM; k0 += 32) {
    __syncthreads();
    gld_lds16(A + (size_t)(m0 + ra0) * DM + k0 + ca0, lA0);
    gld_lds16(A + (size_t)(m0 + ra1) * DM + k0 + ca1, lA1);
    gld_lds16(Bt + (size_t)(n0 + ra0) * DM + k0 + ca0, lB0);
    gld_lds16(Bt + (size_t)(n0 + ra1) * DM + k0 + ca1, lB1);
    __syncthreads();
    bf16x8 af[4], bfv[4];
    for (int mi = 0; mi < 4; ++mi)
      af[mi] = *reinterpret_cast<const bf16x8*>(As + (wm * 64 + mi * 16 + lr) * 32 + lg * 8);
    for (int ni = 0; ni < 4; ++ni)
      bfv[ni] = *reinterpret_cast<const bf16x8*>(Bs + (wn * 64 + ni * 16 + lr) * 32 + lg * 8);
    for (int mi = 0; mi < 4; ++mi)
      for (int ni = 0; ni < 4; ++ni)
        acc[mi][ni] = __builtin_amdgcn_mfma_f32_16x16x32_bf16(af[mi], bfv[ni], acc[mi][ni], 0, 0, 0);
  }

  // ---- phase 1: bias/rotary, stage into LDS ----
  const int mat = n0 >> 10;
  const int c0 = n0 & 1023;
  const int bb = m0 >> 11;
  const int mloc = m0 & 2047;
  const float qscale = (mat == 0) ? C1SC : 1.f;   // fold softmax scale into Q

  for (int mi = 0; mi < 4; ++mi) {
    const int rrel_base = wm * 64 + mi * 16 + lg * 4;
    for (int ni = 0; ni < 4; ++ni) {
      const int crel = wn * 64 + ni * 16 + lr;
      const int c = (c0 + crel);
      const int d = c & 63;
      const float bias = (mat == 0 ? bq : mat == 1 ? bk : bv)[c];
      f32x4 v = acc[mi][ni];
      if (mat < 2) {
        const int jj = d & 15, tt = d >> 4;
        const float fr = __expf(-(float)(jj & 14) * 0.5756462732485115f);
        const float sign = (d & 1) ? 1.f : -1.f;
        for (int j = 0; j < 4; ++j) {
          const int rrel = rrel_base + j;
          const float x = v[j] + bias;
          const float part = __shfl_xor(x, 1, 64);
          const int lqs = mloc + rrel;
          const float fq = temporal[((size_t)bb * LSEQ + lqs) * 4 + tt] * fr;
          float sn, cs;
          __sincosf(fq, &sn, &cs);
          otile[rrel * 136 + crel] = f2bf((x * cs + sign * part * sn) * qscale);
        }
      } else {
        for (int j = 0; j < 4; ++j) {
          const int rrel = rrel_base + j;
          otile[crel * 136 + rrel] = f2bf(v[j] + bias);
        }
      }
    }
  }
  __syncthreads();

  // ---- phase 2: coalesced 16B stores ----
  for (int i = 0; i < 2; ++i) {
    const int h = (c0 >> 6) + i;
    const size_t bh = (size_t)(bb * NH + h);
    if (mat == 0) {
      const size_t base = (bh * LSEQ + mloc) * 64;
#pragma unroll
      for (int kk2 = 0; kk2 < 4; ++kk2) {
        const int e = kk2 * 2048 + tid * 8;
        const int r = e >> 6, d = e & 63;
        *reinterpret_cast<u16x8*>(qbuf + base + e) =
            *reinterpret_cast<const u16x8*>(otile + r * 136 + i * 64 + d);
      }
    } else if (mat == 1) {
      const size_t base = bh * 131072 + (size_t)(mloc >> 5) * 2048;
#pragma unroll
      for (int kk2 = 0; kk2 < 4; ++kk2) {
        const int e = kk2 * 2048 + tid * 8;
        const int r = kk2 * 32 + ((tid >> 1) & 31);
        const int d = ((tid >> 6) & 3) * 16 + (tid & 1) * 8;
        *reinterpret_cast<u16x8*>(kbuf + base + e) =
            *reinterpret_cast<const u16x8*>(otile + r * 136 + i * 64 + d);
      }
    } else {
      const size_t base = bh * 131072 + (size_t)(mloc >> 4) * 1024;
#pragma unroll
      for (int kk2 = 0; kk2 < 4; ++kk2) {
        const int e = kk2 * 2048 + tid * 8;
        const int d = ((tid >> 6) & 1) * 32 + ((tid >> 1) & 31);
        const int r = (kk2 * 2 + (tid >> 7)) * 16 + (tid & 1) * 8;
        *reinterpret_cast<u16x8*>(vtbuf + base + e) =
            *reinterpret_cast<const u16x8*>(otile + (i * 64 + d) * 136 + r);
      }
    }
  }
}

// ---------------- flash attention, swapped-operand 32x32 ----------------
// grid (16 q-blocks, 32 bh); block 256 = 4 waves x 32 q-rows
// Q pre-scaled, mask pre-loaded as MFMA C-init -> scores land directly in log2 domain.
__global__ __launch_bounds__(256) void k_attn(
    const unsigned short* __restrict__ qbuf, const unsigned short* __restrict__ kbuf,
    const unsigned short* __restrict__ vtbuf, const unsigned short* __restrict__ maskCb,
    float* __restrict__ out) {
  __shared__ float otile[4][64][33];
  const int tid = threadIdx.x, lane = tid & 63, wid = tid >> 6;
  const int lq = lane & 31, hi = lane >> 5;
  const int bh = blockIdx.y;
  const int q0 = blockIdx.x * 128 + wid * 32;
  const int qg = q0 + lq;
  const size_t bhL = (size_t)bh * LSEQ;
  const unsigned short* kb = kbuf + (size_t)bh * 131072;
  const unsigned short* vb = vtbuf + (size_t)bh * 131072;
  const unsigned short* mb = maskCb + ((size_t)hi * 2048 + qg) * 16;

  bf16x8 qf[4];
#pragma unroll
  for (int c = 0; c < 4; ++c)
    qf[c] = *reinterpret_cast<const bf16x8*>(qbuf + (bhL + qg) * 64 + c * 16 + hi * 8);

  f32x16 o0 = {}, o1 = {};
  float m2 = -1e30f, l_run = 0.f;

  for (int kv0 = 0; kv0 < LSEQ; kv0 += 64) {
    // mask C-init: 4x16B loads, shift-unpack
    const unsigned short* mt = mb + (size_t)(kv0 >> 6) * (4 * 2048 * 16);
    f32x16 s0 = unpack16(*reinterpret_cast<const u16x8*>(mt),
                         *reinterpret_cast<const u16x8*>(mt + 8));
    f32x16 s1 = unpack16(*reinterpret_cast<const u16x8*>(mt + 2 * 2048 * 16),
                         *reinterpret_cast<const u16x8*>(mt + 2 * 2048 * 16 + 8));

    // S^T = K . Q^T + maskC : scores directly in log2 domain
    const unsigned short* kch = kb + (size_t)(kv0 >> 5) * 2048;
#pragma unroll
    for (int c = 0; c < 4; ++c) {
      bf16x8 k0 = *reinterpret_cast<const bf16x8*>(kch + c * 512 + lq * 16 + hi * 8);
      bf16x8 k1 = *reinterpret_cast<const bf16x8*>(kch + 2048 + c * 512 + lq * 16 + hi * 8);
      s0 = __builtin_amdgcn_mfma_f32_32x32x16_bf16(k0, qf[c], s0, 0, 0, 0);
      s1 = __builtin_amdgcn_mfma_f32_32x32x16_bf16(k1, qf[c], s1, 0, 0, 0);
    }

    // row max: pairwise tree over 32 + one cross-half swap
    float t0[8];
#pragma unroll
    for (int r = 0; r < 8; ++r) t0[r] = fmaxf(fmaxf(s0[r], s0[r + 8]), fmaxf(s1[r], s1[r + 8]));
#pragma unroll
    for (int r = 0; r < 4; ++r) t0[r] = fmaxf(t0[r], t0[r + 4]);
    float loc = fmaxf(fmaxf(t0[0], t0[1]), fmaxf(t0[2], t0[3]));
    loc = fmaxf(loc, __shfl_xor(loc, 32, 64));

    // defer-max (T13): rescale only if some row's max grew by > THR
    if (!__all(loc <= m2 + DEFER_THR)) {
      const float mn = fmaxf(m2, loc);
      const float al = exp2fast(m2 - mn);
      l_run *= al;
#pragma unroll
      for (int r = 0; r < 16; ++r) { o0[r] *= al; o1[r] *= al; }
      m2 = mn;
    }

    // p = 2^(s - m2); row-sum (4 partials for ILP)
    float rs0 = 0.f, rs1 = 0.f, rs2 = 0.f, rs3 = 0.f;
#pragma unroll
    for (int r = 0; r < 4; ++r) {
      s0[r] = exp2fast(s0[r] - m2);      rs0 += s0[r];
      s0[r + 4] = exp2fast(s0[r + 4] - m2);  rs1 += s0[r + 4];
      s0[r + 8] = exp2fast(s0[r + 8] - m2);  rs2 += s0[r + 8];
      s0[r + 12] = exp2fast(s0[r + 12] - m2); rs3 += s0[r + 12];
    }
#pragma unroll
    for (int r = 0; r < 4; ++r) {
      s1[r] = exp2fast(s1[r] - m2);      rs0 += s1[r];
      s1[r + 4] = exp2fast(s1[r + 4] - m2);  rs1 += s1[r + 4];
      s1[r + 8] = exp2fast(s1[r + 8] - m2);  rs2 += s1[r + 8];
      s1[r + 12] = exp2fast(s1[r + 12] - m2); rs3 += s1[r + 12];
    }
    float rs = (rs0 + rs1) + (rs2 + rs3);
    rs += __shfl_xor(rs, 32, 64);
    l_run += rs;

    bf16x8 pf0 = mkfrag(hi, s0[0], s0[1], s0[2], s0[3], s0[4], s0[5], s0[6], s0[7]);
    bf16x8 pf1 = mkfrag(hi, s0[8], s0[9], s0[10], s0[11], s0[12], s0[13], s0[14], s0[15]);
    bf16x8 pf2 = mkfrag(hi, s1[0], s1[1], s1[2], s1[3], s1[4], s1[5], s1[6], s1[7]);
    bf16x8 pf3 = mkfrag(hi, s1[8], s1[9], s1[10], s1[11], s1[12], s1[13], s1[14], s1[15]);

    const unsigned short* vch = vb + (size_t)(kv0 >> 4) * 1024;
#pragma unroll
    for (int ks = 0; ks < 4; ++ks) {
      bf16x8 pf = (ks == 0) ? pf0 : (ks == 1) ? pf1 : (ks == 2) ? pf2 : pf3;
      bf16x8 v0 = *reinterpret_cast<const bf16x8*>(vch + ks * 1024 + lq * 16 + hi * 8);
      bf16x8 v1 = *reinterpret_cast<const bf16x8*>(vch + ks * 1024 + 512 + lq * 16 + hi * 8);
      o0 = __builtin_amdgcn_mfma_f32_32x32x16_bf16(v0, pf, o0, 0, 0, 0);
      o1 = __builtin_amdgcn_mfma_f32_32x32x16_bf16(v1, pf, o1, 0, 0, 0);
    }
  }

  const float inv = 1.f / l_run;
#pragma unroll
  for (int r = 0; r < 16; ++r) {
    const int d = (r & 3) + 8 * (r >> 2) + 4 * hi;
    otile[wid][d][lq] = o0[r] * inv;
    otile[wid][32 + d][lq] = o1[r] * inv;
  }
  __syncthreads();
  const int b = bh >> 4, h = bh & 15;
#pragma unroll
  for (int i = 0; i < 8; ++i) {
    const int u = i * 64 + lane;
    const int q = u >> 4, c4 = u & 15;
    float4 w;
    w.x = otile[wid][c4 * 4 + 0][q];
    w.y = otile[wid][c4 * 4 + 1][q];
    w.z = otile[wid][c4 * 4 + 2][q];
    w.w = otile[wid][c4 * 4 + 3][q];
    *reinterpret_cast<float4*>(out + ((size_t)(b * LSEQ + q0 + q)) * DM + h * 64 + c4 * 4) = w;
  }
}

extern "C" void kernel_launch(void* const* d_in, const int* in_sizes, int n_in,
                              void* d_out, int out_size, void* d_ws, size_t ws_size,
                              hipStream_t stream) {
  const float* data     = (const float*)d_in[0];
  const float* temporal = (const float*)d_in[1];
  const float* mask     = (const float*)d_in[2];
  const float* Wq       = (const float*)d_in[3];
  const float* bq       = (const float*)d_in[4];
  const float* Wk       = (const float*)d_in[5];
  const float* bk       = (const float*)d_in[6];
  const float* Wv       = (const float*)d_in[7];
  const float* bv       = (const float*)d_in[8];
  float* out = (float*)d_out;

  char* ws = (char*)d_ws;
  unsigned short* data_bf = (unsigned short*)(ws);                        // 8 MB (reused by maskCb)
  unsigned short* wt      = (unsigned short*)(ws + (size_t)8  * 1048576); // 6 MB
  unsigned short* qbuf    = (unsigned short*)(ws + (size_t)14 * 1048576); // 8 MB
  unsigned short* kbuf    = (unsigned short*)(ws + (size_t)22 * 1048576); // 8 MB
  unsigned short* vtbuf   = (unsigned short*)(ws + (size_t)30 * 1048576); // 8 MB
  unsigned short* maskCb  = data_bf;  // data_bf dead after k_qkv_gemm; maskC runs after

  hipLaunchKernelGGL(k_convert_data, dim3(4096), dim3(256), 0, stream,
                     data, data_bf, (2 * LSEQ * DM) / 4);
  hipLaunchKernelGGL(k_transpose_w, dim3(16, 16, 3), dim3(256), 0, stream,
                     Wq, Wk, Wv, wt);
  hipLaunchKernelGGL(k_qkv_gemm, dim3(768), dim3(256), 0, stream,
                     data_bf, wt, bq, bk, bv, temporal, qbuf, kbuf, vtbuf);
  hipLaunchKernelGGL(k_maskC, dim3(32, 32), dim3(256), 0, stream,
                     mask, maskCb);
  hipLaunchKernelGGL(k_attn, dim3(16, 32), dim3(256), 0, stream,
                     qbuf, kbuf, vtbuf, maskCb, out);
}